// Round 7
// baseline (2666.506 us; speedup 1.0000x reference)
//
#include <hip/hip_runtime.h>

// TruncatedHistoryAttn, round 7.
// Phase 1 (unchanged): fp32 tiled GEMM  A = H@W1 (-> ws), B2 = H@W2 (-> d_out).
// Phase 2 restructured around a key observation: c = tilde@W3 feeds ONLY the
// score dot-product, so each WG keeps c for its own 64 cols locally and the
// cross-WG exchange shrinks to 5 PARTIAL SCORES per WG per step, published as
// (tag<<32|score) u64 relaxed agent atomics. One fabric round-trip per step
// (data+readiness in one load), no flags, no fences, no publish barrier, no
// memset (0xAA poison is never a valid tag). 2 barriers/step. Score tanh work
// drops 8x (own 64 cols only). W3 stays AGPR-resident (round-5 mechanism).

#define BB 32
#define SS 512
#define DD 512
#define NS 5
#define KWG 8

#define A_ELEMS ((size_t)BB * SS * DD)        // 32 MB
#define YB_U64  ((size_t)BB * 128)            // per batch: 2 slots x 8 wg x 8 u64
#define WS_NEED (A_ELEMS * 4 + YB_U64 * 8)

typedef __attribute__((ext_vector_type(4))) float f32x4;

__device__ __forceinline__ float tanh_v(float x) {
  float e = __expf(2.0f * x);
  return 1.0f - 2.0f / (e + 1.0f);
}

// ---------------- Phase 1: A = H@W1, B2 = H@W2 (fp32) ----------------
__global__ void __launch_bounds__(256) th_phase1(
    const float* __restrict__ H, const float* __restrict__ W1,
    const float* __restrict__ W2, float* __restrict__ A, float* __restrict__ B2) {
  const int tid = threadIdx.x;
  const int mt = blockIdx.x >> 3;
  const int nt = blockIdx.x & 7;
  const int m0 = mt << 6, n0 = nt << 6;
  __shared__ float Ht[64][20];
  __shared__ float Wt1[16][64];
  __shared__ float Wt2[16][64];
  const int tx = tid & 15, ty = tid >> 4;
  const int sr = tid >> 2, sk = (tid & 3) << 2;
  const int wr = tid >> 4, wn = (tid & 15) << 2;
  float a1[4][4] = {{0.f}}, a2[4][4] = {{0.f}};

  for (int k0 = 0; k0 < DD; k0 += 16) {
    float4 hv  = *(const float4*)&H[(size_t)(m0 + sr) * DD + k0 + sk];
    float4 w1v = *(const float4*)&W1[(size_t)(k0 + wr) * DD + n0 + wn];
    float4 w2v = *(const float4*)&W2[(size_t)(k0 + wr) * DD + n0 + wn];
    *(float4*)&Ht[sr][sk]  = hv;
    *(float4*)&Wt1[wr][wn] = w1v;
    *(float4*)&Wt2[wr][wn] = w2v;
    __syncthreads();
#pragma unroll
    for (int kq = 0; kq < 16; kq += 4) {
      float hs[4][4];
#pragma unroll
      for (int i = 0; i < 4; ++i) {
        float4 h4 = *(const float4*)&Ht[ty * 4 + i][kq];
        hs[i][0] = h4.x; hs[i][1] = h4.y; hs[i][2] = h4.z; hs[i][3] = h4.w;
      }
#pragma unroll
      for (int kk = 0; kk < 4; ++kk) {
        float4 w1f = *(const float4*)&Wt1[kq + kk][tx * 4];
        float4 w2f = *(const float4*)&Wt2[kq + kk][tx * 4];
#pragma unroll
        for (int i = 0; i < 4; ++i) {
          float h = hs[i][kk];
          a1[i][0] = fmaf(h, w1f.x, a1[i][0]);
          a1[i][1] = fmaf(h, w1f.y, a1[i][1]);
          a1[i][2] = fmaf(h, w1f.z, a1[i][2]);
          a1[i][3] = fmaf(h, w1f.w, a1[i][3]);
          a2[i][0] = fmaf(h, w2f.x, a2[i][0]);
          a2[i][1] = fmaf(h, w2f.y, a2[i][1]);
          a2[i][2] = fmaf(h, w2f.z, a2[i][2]);
          a2[i][3] = fmaf(h, w2f.w, a2[i][3]);
        }
      }
    }
    __syncthreads();
  }
#pragma unroll
  for (int i = 0; i < 4; ++i) {
    float4 o1 = make_float4(a1[i][0], a1[i][1], a1[i][2], a1[i][3]);
    float4 o2 = make_float4(a2[i][0], a2[i][1], a2[i][2], a2[i][3]);
    size_t off = (size_t)(m0 + ty * 4 + i) * DD + n0 + tx * 4;
    *(float4*)&A[off]  = o1;
    *(float4*)&B2[off] = o2;
  }
}

// ---------------- Phase 2: the recurrence ----------------
// grid 256 = 8 WGs/batch; bid = g*32+b -> siblings share an XCD (mod-8 rr).
__global__ void __launch_bounds__(512) th_phase2(
    const float* __restrict__ H, const float* __restrict__ v,
    const float* __restrict__ W3, const float* __restrict__ A,
    float* __restrict__ Ob,  // d_out: holds B2, rows overwritten with tilde
    unsigned long long* __restrict__ ybuf) {
  const int tid = threadIdx.x;
  const int b  = blockIdx.x & 31;
  const int g  = blockIdx.x >> 5;    // own cols [g*64, g*64+64)
  const int q  = tid >> 6;           // wave 0..7
  const int ln = tid & 63;
  const int kc = ln >> 3;            // matvec k-chunk (64 k each)
  const int sc8 = ln & 7;            // matvec sub-col
  const int colW = (g << 6) + (q << 3) + sc8;  // matvec column
  const int colS = (g << 6) + ln;              // score column
  const int w = ln & 7;              // sibling-WG index this lane polls

  __shared__ float tlds[8 * 72];     // swizzled tilde row: [chunk][64], +8 pad
  __shared__ float a_ring[NS][64];   // h_s@W1, own cols, slot s%5
  __shared__ float c_ring[NS][64];   // tilde_s@W3, own cols, slot s%5

  // W3 slice -> AGPRs: wa[i] = W3[kc*64+i][colW]  (round-5 mechanism)
  float wa[64];
#pragma unroll
  for (int i = 0; i < 64; ++i) {
    float t = W3[(size_t)(kc * 64 + i) * DD + colW];
    asm volatile("v_accvgpr_write_b32 %0, %1" : "=a"(wa[i]) : "v"(t));
  }

  const float v_own = v[colS];
  float tl[NS] = {0.f, 0.f, 0.f, 0.f, 0.f};  // tilde history, full row/thread

  const float* Hb = H + (size_t)b * SS * DD;
  const float* Ab = A + (size_t)b * SS * DD;
  float* Op = Ob + (size_t)b * SS * DD;
  unsigned long long* yb = ybuf + (size_t)b * 128;  // [slot2][wg8][8]

  if (tid < 64) {
#pragma unroll
    for (int s = 0; s < NS; ++s) { a_ring[s][tid] = 0.f; c_ring[s][tid] = 0.f; }
  }

  float h_cur = Hb[tid];       // H row 0 (full row, one elem/thread)
  float b0 = Op[colS];         // B2[0][own col]
  __syncthreads();

  // ---- prologue: scores for T=0 (empty history -> all 5 equal), tag 1
  {
    float s0 = tanh_v(b0) * v_own;
#pragma unroll
    for (int off = 32; off >= 1; off >>= 1) s0 += __shfl_xor(s0, off, 64);
    if (q == 0 && ln == 0) {
      unsigned long long pk =
          (1ull << 32) | (unsigned long long)__float_as_uint(s0);
#pragma unroll
      for (int j = 0; j < NS; ++j)
        __hip_atomic_store(&yb[g * 8 + j], pk, __ATOMIC_RELAXED,
                           __HIP_MEMORY_SCOPE_AGENT);
    }
  }

  for (int t5 = 0; t5 < 515; t5 += 5) {
#pragma unroll
    for (int p = 0; p < NS; ++p) {
      const int T = t5 + p;
      if (T < SS) {
        // ---- prefetch (latency hidden behind poll + step body)
        float h_nxt = 0.f, bNxt = 0.f;
        if (T + 1 < SS) {
          h_nxt = Hb[(size_t)(T + 1) * DD + tid];
          bNxt  = Op[(size_t)(T + 1) * DD + colS];  // B2[T+1][own col]
        }
        float aNew = Ab[(size_t)T * DD + colS];     // A[T][own col]

        // ---- consume scores for T: lane w polls sibling w's 5 (tag|score)
        unsigned long long* ps = yb + (T & 1) * 64 + w * 8;
        const unsigned want = (unsigned)(T + 1);
        unsigned long long p0, p1, p2, p3, p4;
        for (;;) {
          p0 = __hip_atomic_load(&ps[0], __ATOMIC_RELAXED, __HIP_MEMORY_SCOPE_AGENT);
          p1 = __hip_atomic_load(&ps[1], __ATOMIC_RELAXED, __HIP_MEMORY_SCOPE_AGENT);
          p2 = __hip_atomic_load(&ps[2], __ATOMIC_RELAXED, __HIP_MEMORY_SCOPE_AGENT);
          p3 = __hip_atomic_load(&ps[3], __ATOMIC_RELAXED, __HIP_MEMORY_SCOPE_AGENT);
          p4 = __hip_atomic_load(&ps[4], __ATOMIC_RELAXED, __HIP_MEMORY_SCOPE_AGENT);
          if ((unsigned)(p0 >> 32) == want && (unsigned)(p1 >> 32) == want &&
              (unsigned)(p2 >> 32) == want && (unsigned)(p3 >> 32) == want &&
              (unsigned)(p4 >> 32) == want)
            break;
        }
        float sc0 = __uint_as_float((unsigned)p0);
        float sc1 = __uint_as_float((unsigned)p1);
        float sc2 = __uint_as_float((unsigned)p2);
        float sc3 = __uint_as_float((unsigned)p3);
        float sc4 = __uint_as_float((unsigned)p4);
        // sum across the 8 sibling partials (xor over the w bits of ln)
#pragma unroll
        for (int off = 1; off <= 4; off <<= 1) {
          sc0 += __shfl_xor(sc0, off, 64);
          sc1 += __shfl_xor(sc1, off, 64);
          sc2 += __shfl_xor(sc2, off, 64);
          sc3 += __shfl_xor(sc3, off, 64);
          sc4 += __shfl_xor(sc4, off, 64);
        }

        // ---- softmax (redundant per thread, identical results)
        float mx = fmaxf(fmaxf(fmaxf(sc0, sc1), fmaxf(sc2, sc3)), sc4);
        float w0 = __expf(sc0 - mx), w1 = __expf(sc1 - mx), w2 = __expf(sc2 - mx);
        float w3 = __expf(sc3 - mx), w4 = __expf(sc4 - mx);
        float inv = 1.0f / (w0 + w1 + w2 + w3 + w4);

        // ---- tilde_T (full row, per-thread)
        float hh = w0 * tl[p % NS];
        hh = fmaf(w1, tl[(p + 1) % NS], hh);
        hh = fmaf(w2, tl[(p + 2) % NS], hh);
        hh = fmaf(w3, tl[(p + 3) % NS], hh);
        hh = fmaf(w4, tl[(p + 4) % NS], hh);
        hh *= inv;
        float tld = h_cur + fmaxf(hh, 0.f);
        tl[p] = tld;                       // slot T%5 (entry T-5 consumed)
        tlds[q * 72 + ln] = tld;           // swizzled store
        // out row T: dead (all siblings consumed B2[T] before publishing
        // the tag-(T+1) scores we just polled)
        if (g == 0) Op[(size_t)T * DD + tid] = tld;
        __syncthreads();                                   // barrier 1

        // ---- matvec c_T = tilde_T @ W3 (own 64 cols, intra-wave k-reduce)
        float q0 = 0.f, q1 = 0.f, q2 = 0.f, q3 = 0.f;
        const f32x4* tv = (const f32x4*)&tlds[kc * 72];
#pragma unroll
        for (int i = 0; i < 16; ++i) {
          f32x4 t4 = tv[i];
          float x0, x1, x2, x3;
          asm volatile("v_accvgpr_read_b32 %0, %1" : "=v"(x0) : "a"(wa[4 * i + 0]));
          asm volatile("v_accvgpr_read_b32 %0, %1" : "=v"(x1) : "a"(wa[4 * i + 1]));
          asm volatile("v_accvgpr_read_b32 %0, %1" : "=v"(x2) : "a"(wa[4 * i + 2]));
          asm volatile("v_accvgpr_read_b32 %0, %1" : "=v"(x3) : "a"(wa[4 * i + 3]));
          q0 = fmaf(t4.x, x0, q0);
          q1 = fmaf(t4.y, x1, q1);
          q2 = fmaf(t4.z, x2, q2);
          q3 = fmaf(t4.w, x3, q3);
        }
        float cs = (q0 + q1) + (q2 + q3);
        cs += __shfl_xor(cs, 8, 64);
        cs += __shfl_xor(cs, 16, 64);
        cs += __shfl_xor(cs, 32, 64);
        if (ln < 8) c_ring[p][(q << 3) + ln] = cs;  // entrant slot T%5
        if (q == 4) a_ring[p][ln] = aNew;           // entrant A[T], own cols
        __syncthreads();                                   // barrier 2

        // ---- scores for T+1 over own cols (waves 0..4 = history index j)
        if (T + 1 < SS && q < NS) {
          const int slot = (p + 1 + q) % NS;  // history step T-4+q
          float x = a_ring[slot][ln] + bNxt + c_ring[slot][ln];
          float sj = tanh_v(x) * v_own;
#pragma unroll
          for (int off = 32; off >= 1; off >>= 1) sj += __shfl_xor(sj, off, 64);
          if (ln == 0) {
            unsigned long long pk =
                ((unsigned long long)(unsigned)(T + 2) << 32) |
                (unsigned long long)__float_as_uint(sj);
            __hip_atomic_store(&yb[((T + 1) & 1) * 64 + g * 8 + q], pk,
                               __ATOMIC_RELAXED, __HIP_MEMORY_SCOPE_AGENT);
          }
        }
        h_cur = h_nxt;
      }
    }
  }
}

extern "C" void kernel_launch(void* const* d_in, const int* in_sizes, int n_in,
                              void* d_out, int out_size, void* d_ws, size_t ws_size,
                              hipStream_t stream) {
  const float* H  = (const float*)d_in[0];
  const float* v  = (const float*)d_in[1];
  const float* W1 = (const float*)d_in[2];
  const float* W2 = (const float*)d_in[3];
  const float* W3 = (const float*)d_in[4];
  float* out = (float*)d_out;

  if (ws_size < WS_NEED) return;

  float* A = (float*)d_ws;
  unsigned long long* ybuf = (unsigned long long*)((char*)d_ws + A_ELEMS * 4);

  hipLaunchKernelGGL(th_phase1, dim3(256 * 8), dim3(256), 0, stream,
                     H, W1, W2, A, out);
  hipLaunchKernelGGL(th_phase2, dim3(BB * KWG), dim3(512), 0, stream,
                     H, v, W3, A, out, ybuf);
}

// Round 8
// 2265.186 us; speedup vs baseline: 1.1772x; 1.1772x over previous
//
#include <hip/hip_runtime.h>

// TruncatedHistoryAttn, round 8.
// Phase 1 (unchanged): fp32 tiled GEMM  A = H@W1 (-> ws), B2 = H@W2 (-> d_out).
// Phase 2: DUAL-BATCH INTERLEAVE. 128 WGs; group p (8 WGs) serves batches p
// and p+16, alternating per step -> the publish->detect fabric round-trip of
// one batch hides behind the other batch's full step body. W3 slice (64
// floats/thread, AGPR-resident) is SHARED by both batches. Light poll: only
// wave 0 polls (40 lanes x 1 tagged u64; round-7's all-wave poll was the
// regression), sums sibling partials via shfl, broadcasts via LDS. Tagged-u64
// exchange kept: data+tag in one relaxed agent atomic, no flags/fences/memset
// (0xAA poison is never a valid tag). tl ring in LDS (runtime ring indices).

#define BB 32
#define SS 512
#define DD 512
#define NS 5
#define KWG 8

#define A_ELEMS ((size_t)BB * SS * DD)          // 32 MB
#define WS_NEED (A_ELEMS * 4 + (size_t)BB * 128 * 8)

typedef __attribute__((ext_vector_type(4))) float f32x4;

__device__ __forceinline__ float tanh_v(float x) {
  float e = __expf(2.0f * x);
  return 1.0f - 2.0f / (e + 1.0f);
}

// ---------------- Phase 1: A = H@W1, B2 = H@W2 (fp32) ----------------
__global__ void __launch_bounds__(256) th_phase1(
    const float* __restrict__ H, const float* __restrict__ W1,
    const float* __restrict__ W2, float* __restrict__ A, float* __restrict__ B2) {
  const int tid = threadIdx.x;
  const int mt = blockIdx.x >> 3;
  const int nt = blockIdx.x & 7;
  const int m0 = mt << 6, n0 = nt << 6;
  __shared__ float Ht[64][20];
  __shared__ float Wt1[16][64];
  __shared__ float Wt2[16][64];
  const int tx = tid & 15, ty = tid >> 4;
  const int sr = tid >> 2, sk = (tid & 3) << 2;
  const int wr = tid >> 4, wn = (tid & 15) << 2;
  float a1[4][4] = {{0.f}}, a2[4][4] = {{0.f}};

  for (int k0 = 0; k0 < DD; k0 += 16) {
    float4 hv  = *(const float4*)&H[(size_t)(m0 + sr) * DD + k0 + sk];
    float4 w1v = *(const float4*)&W1[(size_t)(k0 + wr) * DD + n0 + wn];
    float4 w2v = *(const float4*)&W2[(size_t)(k0 + wr) * DD + n0 + wn];
    *(float4*)&Ht[sr][sk]  = hv;
    *(float4*)&Wt1[wr][wn] = w1v;
    *(float4*)&Wt2[wr][wn] = w2v;
    __syncthreads();
#pragma unroll
    for (int kq = 0; kq < 16; kq += 4) {
      float hs[4][4];
#pragma unroll
      for (int i = 0; i < 4; ++i) {
        float4 h4 = *(const float4*)&Ht[ty * 4 + i][kq];
        hs[i][0] = h4.x; hs[i][1] = h4.y; hs[i][2] = h4.z; hs[i][3] = h4.w;
      }
#pragma unroll
      for (int kk = 0; kk < 4; ++kk) {
        float4 w1f = *(const float4*)&Wt1[kq + kk][tx * 4];
        float4 w2f = *(const float4*)&Wt2[kq + kk][tx * 4];
#pragma unroll
        for (int i = 0; i < 4; ++i) {
          float h = hs[i][kk];
          a1[i][0] = fmaf(h, w1f.x, a1[i][0]);
          a1[i][1] = fmaf(h, w1f.y, a1[i][1]);
          a1[i][2] = fmaf(h, w1f.z, a1[i][2]);
          a1[i][3] = fmaf(h, w1f.w, a1[i][3]);
          a2[i][0] = fmaf(h, w2f.x, a2[i][0]);
          a2[i][1] = fmaf(h, w2f.y, a2[i][1]);
          a2[i][2] = fmaf(h, w2f.z, a2[i][2]);
          a2[i][3] = fmaf(h, w2f.w, a2[i][3]);
        }
      }
    }
    __syncthreads();
  }
#pragma unroll
  for (int i = 0; i < 4; ++i) {
    float4 o1 = make_float4(a1[i][0], a1[i][1], a1[i][2], a1[i][3]);
    float4 o2 = make_float4(a2[i][0], a2[i][1], a2[i][2], a2[i][3]);
    size_t off = (size_t)(m0 + ty * 4 + i) * DD + n0 + tx * 4;
    *(float4*)&A[off]  = o1;
    *(float4*)&B2[off] = o2;
  }
}

// ---------------- Phase 2: the recurrence, 2 batches per WG ----------------
// grid 128: bid = g*16 + p; group p serves batches p and p+16. Siblings of a
// group: bids {p, 16+p, ..., 112+p} == p (mod 8) -> same XCD under mod-8 rr.
__global__ void __launch_bounds__(512) th_phase2(
    const float* __restrict__ H, const float* __restrict__ v,
    const float* __restrict__ W3, const float* __restrict__ A,
    float* __restrict__ Ob,  // d_out: holds B2, rows overwritten with tilde
    unsigned long long* __restrict__ ybuf) {
  const int tid = threadIdx.x;
  const int p  = blockIdx.x & 15;
  const int g  = blockIdx.x >> 4;              // own cols [g*64, g*64+64)
  const int q  = tid >> 6;                     // wave 0..7
  const int ln = tid & 63;
  const int kc = ln >> 3;                      // matvec k-chunk (64 k each)
  const int colW = (g << 6) + (q << 3) + (ln & 7);
  const int colS = (g << 6) + ln;

  __shared__ float tlds[8 * 72];       // shared by both batches (transient)
  __shared__ float smsc[8];            // broadcast scores   (transient)
  __shared__ float tlL[2][NS][DD];     // tilde ring per batch
  __shared__ float aR[2][NS][64];      // h_s@W1 ring, own cols
  __shared__ float cR[2][NS][64];      // tilde_s@W3 ring, own cols

  // W3 slice -> AGPRs (shared by both batches): wa[i] = W3[kc*64+i][colW]
  float wa[64];
#pragma unroll
  for (int i = 0; i < 64; ++i) {
    float t = W3[(size_t)(kc * 64 + i) * DD + colW];
    asm volatile("v_accvgpr_write_b32 %0, %1" : "=a"(wa[i]) : "v"(t));
  }

  const float v_own = v[colS];

  const float* Hb[2]; const float* Ab[2]; float* Op[2];
  unsigned long long* yb[2];
  float h_cur[2];
#pragma unroll
  for (int m = 0; m < 2; ++m) {
    const int b = p + 16 * m;
    Hb[m] = H + (size_t)b * SS * DD;
    Ab[m] = A + (size_t)b * SS * DD;
    Op[m] = Ob + (size_t)b * SS * DD;
    yb[m] = ybuf + (size_t)b * 128;   // [slot2][wg8][8] u64
    h_cur[m] = Hb[m][tid];
  }

  // zero rings
#pragma unroll
  for (int m = 0; m < 2; ++m) {
#pragma unroll
    for (int s = 0; s < NS; ++s) {
      tlL[m][s][tid] = 0.f;
      if (tid < 64) { aR[m][s][tid] = 0.f; cR[m][s][tid] = 0.f; }
    }
  }
  // prologue: scores for T=0 (empty history -> 5 equal values), tag 1
#pragma unroll
  for (int m = 0; m < 2; ++m) {
    float s0 = tanh_v(Op[m][colS]) * v_own;
#pragma unroll
    for (int off = 32; off >= 1; off >>= 1) s0 += __shfl_xor(s0, off, 64);
    if (q == 0 && ln == 0) {
      unsigned long long pk = (1ull << 32) | (unsigned long long)__float_as_uint(s0);
#pragma unroll
      for (int j = 0; j < NS; ++j)
        __hip_atomic_store(&yb[m][g * 8 + j], pk, __ATOMIC_RELAXED,
                           __HIP_MEMORY_SCOPE_AGENT);
    }
  }
  __syncthreads();

  int rs = 0;  // T % 5
  for (int T = 0; T < SS; ++T) {
#pragma unroll
    for (int m = 0; m < 2; ++m) {
      // ---- prefetch (lands during surrounding compute)
      float h_nxt = 0.f, bN = 0.f;
      if (T + 1 < SS) {
        h_nxt = Hb[m][(size_t)(T + 1) * DD + tid];
        bN    = Op[m][(size_t)(T + 1) * DD + colS];  // B2[T+1][own col]
      }
      float aNew = Ab[m][(size_t)T * DD + colS];     // A[T][own col]

      // ---- consume scores for step T (wave 0 only; tagged u64, 1 load/lane)
      if (q == 0) {
        float sc = 0.f;
        if (ln < 40) {
          const int j = ln >> 3, w = ln & 7;
          unsigned long long* ps = yb[m] + (T & 1) * 64 + w * 8 + j;
          const unsigned want = (unsigned)(T + 1);
          unsigned long long pk;
          do {
            pk = __hip_atomic_load(ps, __ATOMIC_RELAXED, __HIP_MEMORY_SCOPE_AGENT);
          } while ((unsigned)(pk >> 32) != want);
          sc = __uint_as_float((unsigned)pk);
        }
        sc += __shfl_xor(sc, 1, 64);   // sum 8 sibling partials
        sc += __shfl_xor(sc, 2, 64);
        sc += __shfl_xor(sc, 4, 64);
        if (ln < 40 && (ln & 7) == 0) smsc[ln >> 3] = sc;
      }
      __syncthreads();                                   // barrier A

      // ---- softmax (redundant per thread)
      float s0 = smsc[0], s1 = smsc[1], s2 = smsc[2], s3 = smsc[3], s4 = smsc[4];
      float mx = fmaxf(fmaxf(fmaxf(s0, s1), fmaxf(s2, s3)), s4);
      float w0 = __expf(s0 - mx), w1 = __expf(s1 - mx), w2 = __expf(s2 - mx);
      float w3 = __expf(s3 - mx), w4 = __expf(s4 - mx);
      float inv = 1.0f / (w0 + w1 + w2 + w3 + w4);

      // ---- tilde_T (slots rs..rs+4 == history steps T-5..T-1)
      int i1 = rs + 1, i2 = rs + 2, i3 = rs + 3, i4 = rs + 4;
      if (i1 >= 5) i1 -= 5;
      if (i2 >= 5) i2 -= 5;
      if (i3 >= 5) i3 -= 5;
      if (i4 >= 5) i4 -= 5;
      float hh = w0 * tlL[m][rs][tid];
      hh = fmaf(w1, tlL[m][i1][tid], hh);
      hh = fmaf(w2, tlL[m][i2][tid], hh);
      hh = fmaf(w3, tlL[m][i3][tid], hh);
      hh = fmaf(w4, tlL[m][i4][tid], hh);
      hh *= inv;
      float tld = h_cur[m] + fmaxf(hh, 0.f);
      tlL[m][rs][tid] = tld;            // entrant s=T (old s=T-5 consumed)
      tlds[q * 72 + ln] = tld;          // swizzled row for the matvec
      // B2 row T is dead (every sibling consumed it during its step T-1
      // before publishing the tag-(T+1) scores we just polled)
      if (g == 0) Op[m][(size_t)T * DD + tid] = tld;
      __syncthreads();                                   // barrier B

      // ---- matvec c_T = tilde_T @ W3 (own 8 cols/wave, intra-wave k-reduce)
      float q0 = 0.f, q1 = 0.f, q2 = 0.f, q3 = 0.f;
      const f32x4* tv = (const f32x4*)&tlds[kc * 72];
#pragma unroll
      for (int i = 0; i < 16; ++i) {
        f32x4 t4 = tv[i];
        float x0, x1, x2, x3;
        asm volatile("v_accvgpr_read_b32 %0, %1" : "=v"(x0) : "a"(wa[4 * i + 0]));
        asm volatile("v_accvgpr_read_b32 %0, %1" : "=v"(x1) : "a"(wa[4 * i + 1]));
        asm volatile("v_accvgpr_read_b32 %0, %1" : "=v"(x2) : "a"(wa[4 * i + 2]));
        asm volatile("v_accvgpr_read_b32 %0, %1" : "=v"(x3) : "a"(wa[4 * i + 3]));
        q0 = fmaf(t4.x, x0, q0);
        q1 = fmaf(t4.y, x1, q1);
        q2 = fmaf(t4.z, x2, q2);
        q3 = fmaf(t4.w, x3, q3);
      }
      float cs = (q0 + q1) + (q2 + q3);
      cs += __shfl_xor(cs, 8, 64);
      cs += __shfl_xor(cs, 16, 64);
      cs += __shfl_xor(cs, 32, 64);
      if (ln < 8) cR[m][rs][(q << 3) + ln] = cs;  // entrant s=T
      if (q == 7) aR[m][rs][ln] = aNew;           // entrant s=T
      __syncthreads();                                   // barrier C

      // ---- scores for T+1 over own cols (waves 0..4 = history index j)
      if (T + 1 < SS && q < NS) {
        int sl = rs + 1 + q;                // slot for history step T-4+q
        if (sl >= 5) sl -= 5;
        if (sl >= 5) sl -= 5;
        float x = aR[m][sl][ln] + bN + cR[m][sl][ln];
        float sj = tanh_v(x) * v_own;
#pragma unroll
        for (int off = 32; off >= 1; off >>= 1) sj += __shfl_xor(sj, off, 64);
        if (ln == 0) {
          unsigned long long pk =
              ((unsigned long long)(unsigned)(T + 2) << 32) |
              (unsigned long long)__float_as_uint(sj);
          __hip_atomic_store(&yb[m][((T + 1) & 1) * 64 + g * 8 + q], pk,
                             __ATOMIC_RELAXED, __HIP_MEMORY_SCOPE_AGENT);
        }
      }
      h_cur[m] = h_nxt;
    }
    ++rs;
    if (rs >= 5) rs = 0;
  }
}

extern "C" void kernel_launch(void* const* d_in, const int* in_sizes, int n_in,
                              void* d_out, int out_size, void* d_ws, size_t ws_size,
                              hipStream_t stream) {
  const float* H  = (const float*)d_in[0];
  const float* v  = (const float*)d_in[1];
  const float* W1 = (const float*)d_in[2];
  const float* W2 = (const float*)d_in[3];
  const float* W3 = (const float*)d_in[4];
  float* out = (float*)d_out;

  if (ws_size < WS_NEED) return;

  float* A = (float*)d_ws;
  unsigned long long* ybuf = (unsigned long long*)((char*)d_ws + A_ELEMS * 4);

  hipLaunchKernelGGL(th_phase1, dim3(256 * 8), dim3(256), 0, stream,
                     H, W1, W2, A, out);
  hipLaunchKernelGGL(th_phase2, dim3(128), dim3(512), 0, stream,
                     H, v, W3, A, out, ybuf);
}